// Round 6
// baseline (1571.032 us; speedup 1.0000x reference)
//
#include <hip/hip_runtime.h>

// NeighborhoodAttention2D: B=8, C=512, H=W=56, heads=16, d=32, KSZ=7
// Inputs f32 (possibly bf16-rounded values in f32 storage), OUTPUT f32.
// Dtype-agnostic input handling kept (device-side detector).
// q/k/v intermediate bf16 planes in ws. Literal per-thread attention.

typedef unsigned short ushort_t;
typedef unsigned int uint4_t __attribute__((ext_vector_type(4)));

#define BATCH 8
#define HEADS 16
#define HW 3136
#define HH 56
#define DD 32
#define CC 512
#define PLANE ((size_t)BATCH * HEADS * HW * DD)   // 12,845,056 elems per q/k/v tensor
#define OUT_TOT ((size_t)BATCH * CC * HW)         // 12,845,056 f32 outputs

__device__ __forceinline__ float bflo(unsigned int u) {
    union { unsigned int i; float f; } v; v.i = u << 16; return v.f;
}
__device__ __forceinline__ float bfhi(unsigned int u) {
    union { unsigned int i; float f; } v; v.i = u & 0xFFFF0000u; return v.f;
}
__device__ __forceinline__ ushort_t f2bf(float f) {
    union { float f; unsigned int i; } v; v.f = f;
    unsigned int r = v.i + 0x7FFFu + ((v.i >> 16) & 1u);   // RNE
    return (ushort_t)(r >> 16);
}

// ws layout (bytes)
#define OFF_WQ   ((size_t)77070336)                 // after 3 bf16 planes
#define OFF_PW   (OFF_WQ + (size_t)1536 * 512 * 4)  // 80216064
#define OFF_RPB  (OFF_PW + (size_t)512 * 512 * 4)   // 81264640
#define OFF_PB   ((size_t)81275648)                 // 256-aligned after rpb (10816 B)
#define OFF_FLAG (OFF_PB + 2048)                    // 81277696
#define WS_NEED  (OFF_FLAG + 256)                   // 81277952 (~77.5 MB)

__global__ __launch_bounds__(256) void zero_out_f32(float* __restrict__ out) {
    size_t idx = (size_t)blockIdx.x * 256 + threadIdx.x;
    if (idx < OUT_TOT) out[idx] = 0.f;
}

// ---- dtype detect: flag=1 if x is packed bf16, 0 if f32 (incl. bf16-rounded f32) ----
__global__ void detect_kernel(const unsigned int* __restrict__ x,
                              unsigned int* __restrict__ flag) {
    int lane = threadIdx.x;   // 64 threads
    unsigned int w = x[lane];
    unsigned int lo = w & 0xFFFFu;
    float v = bflo(lo);
    bool sane = (lo != 0u) && (fabsf(v) < 16.0f);
    unsigned long long mask = __ballot(sane);
    if (lane == 0) flag[0] = (__popcll(mask) >= 56) ? 1u : 0u;
}

// ---- convert input -> canonical f32 (branch on flag) ----
__global__ __launch_bounds__(256) void conv_kernel(const void* __restrict__ src,
                                                   float* __restrict__ dst, int n,
                                                   const unsigned int* __restrict__ flag) {
    int idx = blockIdx.x * 256 + threadIdx.x;
    if (idx >= n) return;
    if (flag[0]) {
        dst[idx] = bflo((unsigned int)((const ushort_t*)src)[idx]);
    } else {
        dst[idx] = ((const float*)src)[idx];
    }
}

// ---------------- GEMM1: qkv[n][pixel] = sum_k wq[n][k] * x[b][k][pixel] ----------
// tile: 128 n x 64 px, k-tile 32. wq canonical f32; x staged with dtype branch.
__global__ __launch_bounds__(256) void qkv_gemm_simple(const void* __restrict__ xraw,
                                                       const float* __restrict__ w,
                                                       ushort_t* __restrict__ qkv,
                                                       const unsigned int* __restrict__ flag) {
    __shared__ float w_t[128][32];
    __shared__ float x_t[32][68];      // pad 64->68
    int tid = threadIdx.x;
    int b = blockIdx.z;
    int n0 = blockIdx.y * 128;
    int p0 = blockIdx.x * 64;
    int n_loc = tid & 127;
    int pg = tid >> 7;                 // 0 or 1 -> pixel group of 32
    const int is_bf16 = (int)flag[0];

    float acc[32];
    #pragma unroll
    for (int px = 0; px < 32; ++px) acc[px] = 0.f;

    for (int kt = 0; kt < CC / 32; ++kt) {
        __syncthreads();
        #pragma unroll
        for (int r = 0; r < 4; ++r) {          // w tile: 1024 float4 chunks
            int chunk = tid + r * 256;
            int row = chunk >> 3;              // 0..127
            int k4 = (chunk & 7) * 4;          // 0..28
            float4 f = *(const float4*)(w + (size_t)(n0 + row) * CC + kt * 32 + k4);
            w_t[row][k4] = f.x; w_t[row][k4 + 1] = f.y;
            w_t[row][k4 + 2] = f.z; w_t[row][k4 + 3] = f.w;
        }
        if (is_bf16) {                          // x tile from bf16: 256 chunks of 8
            int krow = tid >> 3;                // 0..31
            int px8 = (tid & 7) * 8;            // 0..56
            const ushort_t* src = (const ushort_t*)xraw +
                                  ((size_t)b * CC + kt * 32 + krow) * HW + p0 + px8;
            uint4_t u = *(const uint4_t*)src;
            #pragma unroll
            for (int e = 0; e < 4; ++e) {
                x_t[krow][px8 + 2 * e] = bflo(u[e]);
                x_t[krow][px8 + 2 * e + 1] = bfhi(u[e]);
            }
        } else {                                // x tile from f32: 512 float4 chunks
            #pragma unroll
            for (int r = 0; r < 2; ++r) {
                int chunk = tid + r * 256;
                int krow = chunk >> 4;          // 0..31
                int px4 = (chunk & 15) * 4;     // 0..60
                float4 f = *(const float4*)((const float*)xraw +
                              ((size_t)b * CC + kt * 32 + krow) * HW + p0 + px4);
                x_t[krow][px4] = f.x; x_t[krow][px4 + 1] = f.y;
                x_t[krow][px4 + 2] = f.z; x_t[krow][px4 + 3] = f.w;
            }
        }
        __syncthreads();
        #pragma unroll 8
        for (int k = 0; k < 32; ++k) {
            float a = w_t[n_loc][k];
            #pragma unroll
            for (int px = 0; px < 32; ++px)
                acc[px] += a * x_t[k][pg * 32 + px];
        }
    }
    const float qscale = 0.17677669529663687f;   // 1/sqrt(32)
    int n = n0 + n_loc;
    int which = n >> 9;
    int h = (n >> 5) & 15;
    int dch = n & 31;
    float sc = (which == 0) ? qscale : 1.0f;
    ushort_t* base = qkv + (size_t)which * PLANE + ((size_t)(b * HEADS + h) * HW) * DD + dch;
    #pragma unroll
    for (int px = 0; px < 32; ++px) {
        int pix = p0 + pg * 32 + px;
        base[(size_t)pix * DD] = f2bf(acc[px] * sc);
    }
}

// ---------------- attention (literal): one THREAD per (b, h, pixel) ----------------
__global__ __launch_bounds__(256) void attn_literal(ushort_t* __restrict__ qkv,
                                                    const float* __restrict__ rpb) {
    int idx = blockIdx.x * 256 + threadIdx.x;      // 401408 threads
    int bh = idx / HW;
    int p = idx - bh * HW;
    int b = bh >> 4, h = bh & 15;
    int i = p / HH, j = p - i * HH;
    int si = min(max(i - 3, 0), HH - 7);
    int sj = min(max(j - 3, 0), HH - 7);
    ushort_t* qrow = qkv + (((size_t)b * HEADS + h) * HW + p) * DD;
    const ushort_t* kb = qkv + PLANE + (((size_t)b * HEADS + h) * HW) * DD;
    const ushort_t* vb = qkv + 2 * PLANE + (((size_t)b * HEADS + h) * HW) * DD;

    float q[DD];
    #pragma unroll
    for (int d8 = 0; d8 < DD; d8 += 8) {
        uint4_t u = *(const uint4_t*)(qrow + d8);
        #pragma unroll
        for (int e = 0; e < 4; ++e) {
            q[d8 + 2 * e] = bflo(u[e]);
            q[d8 + 2 * e + 1] = bfhi(u[e]);
        }
    }

    float lg[49];
    float m = -1e30f;
    #pragma unroll
    for (int a = 0; a < 7; ++a) {
        #pragma unroll
        for (int c = 0; c < 7; ++c) {
            int t = a * 7 + c;
            const ushort_t* krow = kb + (size_t)((si + a) * HH + (sj + c)) * DD;
            float dot = 0.f;
            #pragma unroll
            for (int d8 = 0; d8 < DD; d8 += 8) {
                uint4_t u = *(const uint4_t*)(krow + d8);
                #pragma unroll
                for (int e = 0; e < 4; ++e) {
                    dot += q[d8 + 2 * e] * bflo(u[e]);
                    dot += q[d8 + 2 * e + 1] * bfhi(u[e]);
                }
            }
            float bias = rpb[(h * 13 + (si + a - i + 6)) * 13 + (sj + c - j + 6)];
            lg[t] = dot + bias;
            m = fmaxf(m, lg[t]);
        }
    }
    float s = 0.f;
    #pragma unroll
    for (int t = 0; t < 49; ++t) {
        lg[t] = __expf(lg[t] - m);
        s += lg[t];
    }
    float inv = 1.f / s;

    float o[DD];
    #pragma unroll
    for (int d = 0; d < DD; ++d) o[d] = 0.f;
    #pragma unroll
    for (int a = 0; a < 7; ++a) {
        #pragma unroll
        for (int c = 0; c < 7; ++c) {
            int t = a * 7 + c;
            float pt = lg[t] * inv;
            const ushort_t* vrow = vb + (size_t)((si + a) * HH + (sj + c)) * DD;
            #pragma unroll
            for (int d8 = 0; d8 < DD; d8 += 8) {
                uint4_t u = *(const uint4_t*)(vrow + d8);
                #pragma unroll
                for (int e = 0; e < 4; ++e) {
                    o[d8 + 2 * e] += pt * bflo(u[e]);
                    o[d8 + 2 * e + 1] += pt * bfhi(u[e]);
                }
            }
        }
    }
    #pragma unroll
    for (int d = 0; d < DD; ++d) qrow[d] = f2bf(o[d]);   // in-place, read-before-write
}

// ---------------- GEMM3: y[pixel][cout] = sum_c ao[pixel][c] * pw[cout][c] + pb ------
// ao = overwritten q plane, layout [b][h][pix][d], c = h*32+d; k-tile kt == head kt.
// OUTPUT: float32.
__global__ __launch_bounds__(256) void proj_gemm_simple(const ushort_t* __restrict__ ao,
                                                        const float* __restrict__ w,
                                                        const float* __restrict__ bias,
                                                        float* __restrict__ out) {
    __shared__ float w_t[128][32];
    __shared__ float a_t[64][36];      // pad 32->36
    int tid = threadIdx.x;
    int b = blockIdx.z;
    int p0 = blockIdx.x * 64;
    int c0 = blockIdx.y * 128;
    int c_loc = tid & 127;
    int pg = tid >> 7;

    float acc[32];
    #pragma unroll
    for (int px = 0; px < 32; ++px) acc[px] = 0.f;

    const ushort_t* abase = ao + ((size_t)b * HEADS) * HW * DD;

    for (int kt = 0; kt < CC / 32; ++kt) {
        __syncthreads();
        #pragma unroll
        for (int r = 0; r < 4; ++r) {          // w tile (f32)
            int chunk = tid + r * 256;
            int row = chunk >> 3;
            int k4 = (chunk & 7) * 4;
            float4 f = *(const float4*)(w + (size_t)(c0 + row) * CC + kt * 32 + k4);
            w_t[row][k4] = f.x; w_t[row][k4 + 1] = f.y;
            w_t[row][k4 + 2] = f.z; w_t[row][k4 + 3] = f.w;
        }
        {                                       // a tile: 64 px rows x 32 k (bf16 -> f32)
            int row = tid >> 2;                 // 0..63
            int k8 = (tid & 3) * 8;             // 0,8,16,24
            uint4_t u = *(const uint4_t*)(abase + ((size_t)kt * HW + p0 + row) * DD + k8);
            #pragma unroll
            for (int e = 0; e < 4; ++e) {
                a_t[row][k8 + 2 * e] = bflo(u[e]);
                a_t[row][k8 + 2 * e + 1] = bfhi(u[e]);
            }
        }
        __syncthreads();
        #pragma unroll 8
        for (int k = 0; k < 32; ++k) {
            float bv = w_t[c_loc][k];
            #pragma unroll
            for (int px = 0; px < 32; ++px)
                acc[px] += bv * a_t[pg * 32 + px][k];
        }
    }
    int cch = c0 + c_loc;
    float bz = bias[cch];
    float* dst = out + ((size_t)b * CC + cch) * HW + p0 + pg * 32;
    #pragma unroll
    for (int px = 0; px < 32; ++px) {
        dst[px] = acc[px] + bz;
    }
}

extern "C" void kernel_launch(void* const* d_in, const int* in_sizes, int n_in,
                              void* d_out, int out_size, void* d_ws, size_t ws_size,
                              hipStream_t stream) {
    const void* x = d_in[0];
    const void* qkv_w = d_in[1];
    const void* rpb = d_in[2];
    const void* proj_w = d_in[3];
    const void* proj_b = d_in[4];
    float* out = (float*)d_out;

    if (ws_size < WS_NEED) {
        zero_out_f32<<<dim3((int)((OUT_TOT + 255) / 256)), dim3(256), 0, stream>>>(out);
        return;
    }
    char* ws = (char*)d_ws;
    ushort_t* qkv = (ushort_t*)ws;
    float* wq_f = (float*)(ws + OFF_WQ);
    float* pw_f = (float*)(ws + OFF_PW);
    float* rpb_f = (float*)(ws + OFF_RPB);
    float* pb_f = (float*)(ws + OFF_PB);
    unsigned int* flag = (unsigned int*)(ws + OFF_FLAG);

    detect_kernel<<<dim3(1), dim3(64), 0, stream>>>((const unsigned int*)x, flag);
    conv_kernel<<<dim3((1536 * 512 + 255) / 256), dim3(256), 0, stream>>>(qkv_w, wq_f, 1536 * 512, flag);
    conv_kernel<<<dim3((512 * 512 + 255) / 256), dim3(256), 0, stream>>>(proj_w, pw_f, 512 * 512, flag);
    conv_kernel<<<dim3((2704 + 255) / 256), dim3(256), 0, stream>>>(rpb, rpb_f, 2704, flag);
    conv_kernel<<<dim3(2), dim3(256), 0, stream>>>(proj_b, pb_f, 512, flag);

    qkv_gemm_simple<<<dim3(49, 12, 8), dim3(256), 0, stream>>>(x, wq_f, qkv, flag);
    attn_literal<<<dim3(1568), dim3(256), 0, stream>>>(qkv, rpb_f);
    proj_gemm_simple<<<dim3(49, 4, 8), dim3(256), 0, stream>>>(qkv, pw_f, pb_f, out);
}

// Round 8
// 507.926 us; speedup vs baseline: 3.0930x; 3.0930x over previous
//
#include <hip/hip_runtime.h>

// NeighborhoodAttention2D: B=8, C=512, H=W=56, heads=16, d=32, KSZ=7
// Inputs f32, OUTPUT f32. bf16 intermediates (q/k/v planes in ws), f32 accumulation.
// Round 8: green round-6 pipeline with both GEMMs replaced by MFMA versions.
//  - GEMM1 stages x directly from [b][c][hw] (in-LDS transpose) -- no transpose kernel.
//  - Attention: literal per-thread version (validated green in round 6), unchanged.
//  - GEMM3: MFMA with f32 float4 epilogue.

typedef unsigned short ushort_t;
typedef short bf16x8 __attribute__((ext_vector_type(8)));      // 8 bf16 = 4 VGPRs (MFMA A/B frag)
typedef float f32x4 __attribute__((ext_vector_type(4)));       // MFMA C/D frag
typedef unsigned int uint4_t __attribute__((ext_vector_type(4)));
typedef unsigned int uint2_t __attribute__((ext_vector_type(2)));

#define BATCH 8
#define HEADS 16
#define HW 3136
#define HH 56
#define DD 32
#define CC 512
#define PLANE ((size_t)BATCH * HEADS * HW * DD)   // 12,845,056 elems per q/k/v plane
#define OUT_TOT ((size_t)BATCH * CC * HW)
#define LP 40                                      // LDS row pitch (elems); 80B rows

__device__ __forceinline__ float bflo(unsigned int u) {
    union { unsigned int i; float f; } v; v.i = u << 16; return v.f;
}
__device__ __forceinline__ float bfhi(unsigned int u) {
    union { unsigned int i; float f; } v; v.i = u & 0xFFFF0000u; return v.f;
}
__device__ __forceinline__ ushort_t f2bf(float f) {
    union { float f; unsigned int i; } v; v.f = f;
    unsigned int r = v.i + 0x7FFFu + ((v.i >> 16) & 1u);   // RNE
    return (ushort_t)(r >> 16);
}
__device__ __forceinline__ unsigned int pack2(float a, float b) {
    return (unsigned int)f2bf(a) | ((unsigned int)f2bf(b) << 16);
}

__global__ __launch_bounds__(256) void zero_out_f32(float* __restrict__ out) {
    size_t idx = (size_t)blockIdx.x * 256 + threadIdx.x;
    if (idx < OUT_TOT) out[idx] = 0.f;
}

// ---------------- GEMM1: qkv^T = qkv_w (1536x512 f32) . x (f32, [b][k][pixel]) ----------
// D[n][pixel]; tile 128 (n) x 64 (pixel), BK=32, 4 waves (2x2), 4x2 subtiles/wave.
// B-tile staged straight from x with in-LDS transpose (lane = pixel, coalesced).
__global__ __launch_bounds__(256) void qkv_gemm_kernel(const float* __restrict__ x,
                                                       const float* __restrict__ w,
                                                       ushort_t* __restrict__ qkv) {
    __shared__ __align__(16) ushort_t lds_p[128 * LP];
    __shared__ __align__(16) ushort_t lds_q[64 * LP];
    const int K = CC;
    int tid = threadIdx.x;
    int b = blockIdx.z;
    int n0 = blockIdx.y * 128;
    int p0 = blockIdx.x * 64;
    int lane = tid & 63, wv = tid >> 6;
    int wp = wv & 1, wq = wv >> 1;
    int quad = lane >> 4, l15 = lane & 15;

    f32x4 acc[4][2];
    #pragma unroll
    for (int i = 0; i < 4; ++i)
        #pragma unroll
        for (int jq = 0; jq < 2; ++jq) acc[i][jq] = (f32x4){0.f, 0.f, 0.f, 0.f};

    // B staging indices: one pixel per thread-slot, 8 k's
    int spx = tid & 63;                 // pixel 0..63
    int sk8 = (tid >> 6) * 8;           // k offset 0,8,16,24

    for (int kt = 0; kt < K / 32; ++kt) {
        __syncthreads();
        #pragma unroll
        for (int r = 0; r < 2; ++r) {      // A (weights f32->bf16): 512 chunks of 8
            int chunk = tid + r * 256;
            int row = chunk >> 2, k8 = (chunk & 3) * 8;
            const float* src = w + (size_t)(n0 + row) * K + kt * 32 + k8;
            float4 f0 = *(const float4*)src;
            float4 f1 = *(const float4*)(src + 4);
            uint4_t u;
            u[0] = pack2(f0.x, f0.y);
            u[1] = pack2(f0.z, f0.w);
            u[2] = pack2(f1.x, f1.y);
            u[3] = pack2(f1.z, f1.w);
            *(uint4_t*)&lds_p[row * LP + k8] = u;
        }
        {                                   // B (x f32, [k][pixel] -> LDS [pixel][k])
            const float* xcol = x + ((size_t)b * CC + kt * 32 + sk8) * HW + p0 + spx;
            float v0 = xcol[0];
            float v1 = xcol[(size_t)HW];
            float v2 = xcol[(size_t)2 * HW];
            float v3 = xcol[(size_t)3 * HW];
            float v4 = xcol[(size_t)4 * HW];
            float v5 = xcol[(size_t)5 * HW];
            float v6 = xcol[(size_t)6 * HW];
            float v7 = xcol[(size_t)7 * HW];
            uint4_t u;
            u[0] = pack2(v0, v1);
            u[1] = pack2(v2, v3);
            u[2] = pack2(v4, v5);
            u[3] = pack2(v6, v7);
            *(uint4_t*)&lds_q[spx * LP + sk8] = u;
        }
        __syncthreads();
        bf16x8 afrag[4], bfrag[2];
        #pragma unroll
        for (int i = 0; i < 4; ++i)
            afrag[i] = *(const bf16x8*)&lds_p[(wp * 64 + i * 16 + l15) * LP + quad * 8];
        #pragma unroll
        for (int jq = 0; jq < 2; ++jq)
            bfrag[jq] = *(const bf16x8*)&lds_q[(wq * 32 + jq * 16 + l15) * LP + quad * 8];
        #pragma unroll
        for (int i = 0; i < 4; ++i)
            #pragma unroll
            for (int jq = 0; jq < 2; ++jq)
                acc[i][jq] = __builtin_amdgcn_mfma_f32_16x16x32_bf16(afrag[i], bfrag[jq],
                                                                     acc[i][jq], 0, 0, 0);
    }
    const float qscale = 0.17677669529663687f;   // 1/sqrt(32)
    #pragma unroll
    for (int i = 0; i < 4; ++i) {
        int nbase = n0 + wp * 64 + i * 16 + quad * 4;    // 4 consecutive n = 4 consecutive d
        int which = nbase >> 9;
        int h = (nbase >> 5) & 15;
        int dch = nbase & 31;
        float sc = (which == 0) ? qscale : 1.0f;
        #pragma unroll
        for (int jq = 0; jq < 2; ++jq) {
            int pix = p0 + wq * 32 + jq * 16 + l15;
            uint2_t v;
            v[0] = pack2(acc[i][jq][0] * sc, acc[i][jq][1] * sc);
            v[1] = pack2(acc[i][jq][2] * sc, acc[i][jq][3] * sc);
            ushort_t* dst = qkv + (size_t)which * PLANE +
                            ((((size_t)b * HEADS + h) * HW + pix) * DD + dch);
            *(uint2_t*)dst = v;
        }
    }
}

// ---------------- attention (literal, validated): one THREAD per (b, h, pixel) ----------------
__global__ __launch_bounds__(256) void attn_literal(ushort_t* __restrict__ qkv,
                                                    const float* __restrict__ rpb) {
    int idx = blockIdx.x * 256 + threadIdx.x;      // 401408 threads
    int bh = idx / HW;
    int p = idx - bh * HW;
    int b = bh >> 4, h = bh & 15;
    int i = p / HH, j = p - i * HH;
    int si = min(max(i - 3, 0), HH - 7);
    int sj = min(max(j - 3, 0), HH - 7);
    ushort_t* qrow = qkv + (((size_t)b * HEADS + h) * HW + p) * DD;
    const ushort_t* kb = qkv + PLANE + (((size_t)b * HEADS + h) * HW) * DD;
    const ushort_t* vb = qkv + 2 * PLANE + (((size_t)b * HEADS + h) * HW) * DD;

    float q[DD];
    #pragma unroll
    for (int d8 = 0; d8 < DD; d8 += 8) {
        uint4_t u = *(const uint4_t*)(qrow + d8);
        #pragma unroll
        for (int e = 0; e < 4; ++e) {
            q[d8 + 2 * e] = bflo(u[e]);
            q[d8 + 2 * e + 1] = bfhi(u[e]);
        }
    }

    float lg[49];
    float m = -1e30f;
    #pragma unroll
    for (int a = 0; a < 7; ++a) {
        #pragma unroll
        for (int c = 0; c < 7; ++c) {
            int t = a * 7 + c;
            const ushort_t* krow = kb + (size_t)((si + a) * HH + (sj + c)) * DD;
            float dot = 0.f;
            #pragma unroll
            for (int d8 = 0; d8 < DD; d8 += 8) {
                uint4_t u = *(const uint4_t*)(krow + d8);
                #pragma unroll
                for (int e = 0; e < 4; ++e) {
                    dot += q[d8 + 2 * e] * bflo(u[e]);
                    dot += q[d8 + 2 * e + 1] * bfhi(u[e]);
                }
            }
            float bias = rpb[(h * 13 + (si + a - i + 6)) * 13 + (sj + c - j + 6)];
            lg[t] = dot + bias;
            m = fmaxf(m, lg[t]);
        }
    }
    float s = 0.f;
    #pragma unroll
    for (int t = 0; t < 49; ++t) {
        lg[t] = __expf(lg[t] - m);
        s += lg[t];
    }
    float inv = 1.f / s;

    float o[DD];
    #pragma unroll
    for (int d = 0; d < DD; ++d) o[d] = 0.f;
    #pragma unroll
    for (int a = 0; a < 7; ++a) {
        #pragma unroll
        for (int c = 0; c < 7; ++c) {
            int t = a * 7 + c;
            float pt = lg[t] * inv;
            const ushort_t* vrow = vb + (size_t)((si + a) * HH + (sj + c)) * DD;
            #pragma unroll
            for (int d8 = 0; d8 < DD; d8 += 8) {
                uint4_t u = *(const uint4_t*)(vrow + d8);
                #pragma unroll
                for (int e = 0; e < 4; ++e) {
                    o[d8 + 2 * e] += pt * bflo(u[e]);
                    o[d8 + 2 * e + 1] += pt * bfhi(u[e]);
                }
            }
        }
    }
    #pragma unroll
    for (int d = 0; d < DD; ++d) qrow[d] = f2bf(o[d]);   // in-place, read-before-write
}

// ---------------- GEMM3: y = attn_out (bf16, q plane) . proj_w^T (f32) + b; OUT f32 -----
// attn_out layout [b][h][pix][d]; k-tile kt == head kt.
// D[pixel][c]; tile 64 (pixel) x 128 (c), BK=32, 4 waves (2x2), 2x4 subtiles/wave.
__global__ __launch_bounds__(256) void proj_gemm_kernel(const ushort_t* __restrict__ ao,
                                                        const float* __restrict__ w,
                                                        const float* __restrict__ bias,
                                                        float* __restrict__ out) {
    __shared__ __align__(16) ushort_t lds_p[64 * LP];
    __shared__ __align__(16) ushort_t lds_q[128 * LP];
    const int K = CC;
    int tid = threadIdx.x;
    int b = blockIdx.z;
    int p0 = blockIdx.x * 64;
    int c0 = blockIdx.y * 128;
    int lane = tid & 63, wv = tid >> 6;
    int wp = wv & 1, wq = wv >> 1;
    int quad = lane >> 4, l15 = lane & 15;

    f32x4 acc[2][4];
    #pragma unroll
    for (int i = 0; i < 2; ++i)
        #pragma unroll
        for (int jq = 0; jq < 4; ++jq) acc[i][jq] = (f32x4){0.f, 0.f, 0.f, 0.f};

    const ushort_t* abase = ao + ((size_t)b * HEADS) * HW * DD;   // b's 16 head planes

    for (int kt = 0; kt < K / 32; ++kt) {
        __syncthreads();
        {                                   // A (attn out bf16): rows = pixels of head kt
            int row = tid >> 2, k8 = (tid & 3) * 8;
            uint4_t u = *(const uint4_t*)(abase + ((size_t)kt * HW + p0 + row) * DD + k8);
            *(uint4_t*)&lds_p[row * LP + k8] = u;
        }
        #pragma unroll
        for (int r = 0; r < 2; ++r) {       // B (proj_w f32->bf16): 512 chunks of 8
            int chunk = tid + r * 256;
            int row = chunk >> 2, k8 = (chunk & 3) * 8;
            const float* src = w + (size_t)(c0 + row) * K + kt * 32 + k8;
            float4 f0 = *(const float4*)src;
            float4 f1 = *(const float4*)(src + 4);
            uint4_t u;
            u[0] = pack2(f0.x, f0.y);
            u[1] = pack2(f0.z, f0.w);
            u[2] = pack2(f1.x, f1.y);
            u[3] = pack2(f1.z, f1.w);
            *(uint4_t*)&lds_q[row * LP + k8] = u;
        }
        __syncthreads();
        bf16x8 afrag[2], bfrag[4];
        #pragma unroll
        for (int i = 0; i < 2; ++i)
            afrag[i] = *(const bf16x8*)&lds_p[(wp * 32 + i * 16 + l15) * LP + quad * 8];
        #pragma unroll
        for (int jq = 0; jq < 4; ++jq)
            bfrag[jq] = *(const bf16x8*)&lds_q[(wq * 64 + jq * 16 + l15) * LP + quad * 8];
        #pragma unroll
        for (int i = 0; i < 2; ++i)
            #pragma unroll
            for (int jq = 0; jq < 4; ++jq)
                acc[i][jq] = __builtin_amdgcn_mfma_f32_16x16x32_bf16(afrag[i], bfrag[jq],
                                                                     acc[i][jq], 0, 0, 0);
    }
    #pragma unroll
    for (int i = 0; i < 2; ++i) {
        int pix = p0 + wp * 32 + i * 16 + quad * 4;      // 4 consecutive pixels
        #pragma unroll
        for (int jq = 0; jq < 4; ++jq) {
            int cch = c0 + wq * 64 + jq * 16 + l15;
            float bz = bias[cch];
            float4 v;
            v.x = acc[i][jq][0] + bz;
            v.y = acc[i][jq][1] + bz;
            v.z = acc[i][jq][2] + bz;
            v.w = acc[i][jq][3] + bz;
            float* dst = out + ((size_t)b * CC + cch) * HW + pix;
            *(float4*)dst = v;
        }
    }
}

extern "C" void kernel_launch(void* const* d_in, const int* in_sizes, int n_in,
                              void* d_out, int out_size, void* d_ws, size_t ws_size,
                              hipStream_t stream) {
    const float* x = (const float*)d_in[0];
    const float* qkv_w = (const float*)d_in[1];
    const float* rpb = (const float*)d_in[2];
    const float* proj_w = (const float*)d_in[3];
    const float* proj_b = (const float*)d_in[4];
    float* out = (float*)d_out;

    size_t need = 3 * PLANE * sizeof(ushort_t);   // 73.5 MB
    if (ws_size < need) {
        zero_out_f32<<<dim3((int)((OUT_TOT + 255) / 256)), dim3(256), 0, stream>>>(out);
        return;
    }

    ushort_t* qkv = (ushort_t*)d_ws;         // q/k/v: 3 bf16 planes

    qkv_gemm_kernel<<<dim3(49, 12, 8), dim3(256), 0, stream>>>(x, qkv_w, qkv);
    attn_literal<<<dim3(1568), dim3(256), 0, stream>>>(qkv, rpb);
    proj_gemm_kernel<<<dim3(49, 4, 8), dim3(256), 0, stream>>>(qkv, proj_w, proj_b, out);
}